// Round 3
// baseline (435.022 us; speedup 1.0000x reference)
//
#include <hip/hip_runtime.h>
#include <hip/hip_bf16.h>
#include <stdint.h>

// Problem constants
#define BATCH   4096
#define CONTENT 200
#define EMBED   128
#define HIDDEN  1024
#define KDIM    (CONTENT*EMBED)   // 25600
#define KSTEPS64 (KDIM/64)        // 400 K-tiles of 64
#define SPLITK  2
#define KCHUNK64 200              // K-tiles per split chunk (exact, both even start)

typedef __bf16 bf16_t;
typedef __bf16 bf16x8 __attribute__((ext_vector_type(8)));
typedef float  f32x4  __attribute__((ext_vector_type(4)));

// Workspace layout (bytes)
#define WS_EMBT  0ull                      // emb bf16 [50000][128] = 12,800,000 B
#define WS_W1    12800000ull               // w1 bf16 [1024][25600] = 52,428,800 B
#define WS_HP    65228800ull               // 2 x f32 [4096][1024]  = 33,554,432 B
#define HP_STRIDE 4194304ull               // floats per partial buffer

__device__ __forceinline__ void gload_lds16(const void* g, void* l) {
  __builtin_amdgcn_global_load_lds(
      (const __attribute__((address_space(1))) uint32_t*)g,
      (__attribute__((address_space(3))) uint32_t*)l, 16, 0, 0);
}

// ---------------- Kernel 1: fused prep — cast emb (zero row 0) + cast w1 ----------------
__global__ __launch_bounds__(256) void k_prep(const float* __restrict__ emb,
                                              const float* __restrict__ w1,
                                              bf16_t* __restrict__ embT,
                                              bf16_t* __restrict__ w1T) {
  if (blockIdx.x < 320) {
    // emb: 50000*128/8 = 800,000 units of 8
    const int NU = 800000;
    int stride = 320 * 256;
    for (int u = blockIdx.x * 256 + threadIdx.x; u < NU; u += stride) {
      const float4* s = (const float4*)(emb + (size_t)u * 8);
      float4 f0 = s[0], f1 = s[1];
      float sc = (u >> 4) == 0 ? 0.0f : 1.0f;   // padding_idx = 0
      bf16x8 r;
      r[0]=(bf16_t)(f0.x*sc); r[1]=(bf16_t)(f0.y*sc); r[2]=(bf16_t)(f0.z*sc); r[3]=(bf16_t)(f0.w*sc);
      r[4]=(bf16_t)(f1.x*sc); r[5]=(bf16_t)(f1.y*sc); r[6]=(bf16_t)(f1.z*sc); r[7]=(bf16_t)(f1.w*sc);
      *(bf16x8*)(embT + (size_t)u * 8) = r;
    }
  } else {
    // w1: 1024*25600/8 = 3,276,800 units of 8
    const long long NU = 3276800;
    long long stride = 2048LL * 256;
    for (long long u = (long long)(blockIdx.x - 320) * 256 + threadIdx.x; u < NU; u += stride) {
      const float4* s = (const float4*)(w1 + u * 8);
      float4 f0 = s[0], f1 = s[1];
      bf16x8 r;
      r[0]=(bf16_t)f0.x; r[1]=(bf16_t)f0.y; r[2]=(bf16_t)f0.z; r[3]=(bf16_t)f0.w;
      r[4]=(bf16_t)f1.x; r[5]=(bf16_t)f1.y; r[6]=(bf16_t)f1.z; r[7]=(bf16_t)f1.w;
      *(bf16x8*)(w1T + u * 8) = r;
    }
  }
}

// ---------------- Kernel 2: fused gather-GEMM, double-buffered pipeline ----------------
// Structure: stage tile t+2 AFTER the sync that ends tile t, into the buffer tile t
// just vacated. The __syncthreads auto-drain (vmcnt(0)) then only waits on loads
// issued a full tile ago (covered by MFMA compute) — removes the m97-style stall.
__global__ __launch_bounds__(256) void k_gemm(const int* __restrict__ x,
                                              const bf16_t* __restrict__ embT,
                                              const bf16_t* __restrict__ W,
                                              float* __restrict__ hp) {
  __shared__ char smem[65536];          // 2 buffers x (A 16KB | B 16KB)
  const int tid = threadIdx.x;
  const int w = tid >> 6, l = tid & 63;
  const int m0 = blockIdx.x * 128;
  const int n0 = blockIdx.y * 128;
  const int chunk = blockIdx.z;
  const int ks_begin = chunk * KCHUNK64;   // 0 or 200 (even)
  const int nt = KCHUNK64;                 // 200 K-tiles per chunk

  // --- staging geometry (verified round 2):
  // granule rd: LDS byte = rd*4096 + tid*16 -> row = rd*32 + (tid>>3), slot = tid&7
  // swizzle: LDS slot s at row r holds global k-slot s ^ (r&7)
  const int rbase = tid >> 3;
  const int sg = (tid & 7) ^ (rbase & 7);
  const char* embB = (const char*)embT;
  const char* Wb = (const char*)W;

  const char* bsrc[4];
  #pragma unroll
  for (int rd = 0; rd < 4; ++rd)
    bsrc[rd] = Wb + (size_t)(n0 + rd * 32 + rbase) * (KDIM * 2)
                  + (size_t)ks_begin * 128 + sg * 16;

  // x-index pipeline: xv = token for tiles currently being issued, xn = next token
  int tokc = ks_begin >> 1;
  int xv[4], xn[4];
  #pragma unroll
  for (int rd = 0; rd < 4; ++rd)
    xv[rd] = x[(m0 + rd * 32 + rbase) * CONTENT + tokc];
  #pragma unroll
  for (int rd = 0; rd < 4; ++rd)
    xn[rd] = x[(m0 + rd * 32 + rbase) * CONTENT + tokc + 1];

#define ISSUE(koff, base)                                                     \
  { _Pragma("unroll")                                                         \
    for (int rd = 0; rd < 4; ++rd) {                                          \
      gload_lds16(embB + (size_t)xv[rd] * 256 + (koff) + sg * 16,             \
                  smem + (base) + w * 1024 + rd * 4096);                      \
      gload_lds16(bsrc[rd], smem + (base) + 16384 + w * 1024 + rd * 4096);    \
      bsrc[rd] += 128;                                                        \
    } }

  // --- fragment geometry (verified round 2)
  const int wr = w >> 1, wc = w & 1;
  const int lane_r = l & 15;
  const int g = l >> 4;

  f32x4 acc[4][4];
  #pragma unroll
  for (int i = 0; i < 4; ++i)
    #pragma unroll
    for (int j = 0; j < 4; ++j)
      acc[i][j] = (f32x4){0.f, 0.f, 0.f, 0.f};

  // prologue: stage tile 0 -> buf0, tile 1 -> buf1
  ISSUE(0, 0);
  ISSUE(128, 32768);
  __syncthreads();                      // drain prologue stages (once)

  for (int t = 0; t < nt; ++t) {
    const char* AsB = smem + ((t & 1) << 15);
    const char* BsB = AsB + 16384;

    #pragma unroll
    for (int kk = 0; kk < 2; ++kk) {
      bf16x8 af[4], bfr[4];
      #pragma unroll
      for (int i = 0; i < 4; ++i) {
        int rowa = wr * 64 + i * 16 + lane_r;
        int rowb = wc * 64 + i * 16 + lane_r;
        int slot = ((kk << 2) | g) ^ (lane_r & 7);
        af[i]  = *(const bf16x8*)(AsB + rowa * 128 + slot * 16);
        bfr[i] = *(const bf16x8*)(BsB + rowb * 128 + slot * 16);
      }
      __builtin_amdgcn_s_setprio(1);
      #pragma unroll
      for (int i = 0; i < 4; ++i)
        #pragma unroll
        for (int j = 0; j < 4; ++j)
          acc[i][j] = __builtin_amdgcn_mfma_f32_16x16x32_bf16(af[i], bfr[j], acc[i][j], 0, 0, 0);
      __builtin_amdgcn_s_setprio(0);
    }

    __syncthreads();  // all waves done reading buf[t&1]; 1-tile-old stages drained

    int tt = t + 2;
    if (tt < nt) {
      int ks = ks_begin + tt;
      if ((ks & 1) == 0) {              // advance token
        tokc = ks >> 1;
        #pragma unroll
        for (int rd = 0; rd < 4; ++rd) xv[rd] = xn[rd];
        int nxt = tokc + 1; if (nxt > CONTENT - 1) nxt = CONTENT - 1;
        #pragma unroll
        for (int rd = 0; rd < 4; ++rd)
          xn[rd] = x[(m0 + rd * 32 + rbase) * CONTENT + nxt];
      }
      ISSUE((ks & 1) << 7, (t & 1) << 15);
    }
  }
#undef ISSUE

  // Epilogue: C/D layout col = lane&15, row = (lane>>4)*4 + reg  [HW-verified]
  float* hout = hp + (size_t)chunk * HP_STRIDE;
  const int colBase = n0 + wc * 64 + lane_r;
  const int rowBase = m0 + wr * 64 + (l >> 4) * 4;
  #pragma unroll
  for (int i = 0; i < 4; ++i)
    #pragma unroll
    for (int j = 0; j < 4; ++j)
      #pragma unroll
      for (int r = 0; r < 4; ++r)
        hout[(size_t)(rowBase + i * 16 + r) * HIDDEN + colBase + j * 16] = acc[i][j][r];
}

// ---------------- Kernel 3: sum partials + bias + relu + layer2 + softmax ----------------
__global__ __launch_bounds__(256) void k_final(const float* __restrict__ hp,
                                               const float* __restrict__ b1,
                                               const float* __restrict__ w2,
                                               const float* __restrict__ b2,
                                               float* __restrict__ out) {
  const int tid = threadIdx.x;
  const int w = tid >> 6, l = tid & 63;
  const int m = blockIdx.x * 4 + w;     // one wave per batch row
  const float* r0 = hp + (size_t)m * HIDDEN;
  const float* r1 = r0 + HP_STRIDE;
  float l0 = 0.f, l1 = 0.f;
  #pragma unroll
  for (int t = 0; t < 4; ++t) {
    int j = t * 256 + l * 4;
    float4 p0 = *(const float4*)(r0 + j);
    float4 p1 = *(const float4*)(r1 + j);
    float4 bb = *(const float4*)(b1 + j);
    float4 wa = *(const float4*)(w2 + j);
    float4 wb = *(const float4*)(w2 + HIDDEN + j);
    float h;
    h = p0.x + p1.x + bb.x; h = fmaxf(h, 0.f); l0 += h * wa.x; l1 += h * wb.x;
    h = p0.y + p1.y + bb.y; h = fmaxf(h, 0.f); l0 += h * wa.y; l1 += h * wb.y;
    h = p0.z + p1.z + bb.z; h = fmaxf(h, 0.f); l0 += h * wa.z; l1 += h * wb.z;
    h = p0.w + p1.w + bb.w; h = fmaxf(h, 0.f); l0 += h * wa.w; l1 += h * wb.w;
  }
  #pragma unroll
  for (int off = 32; off > 0; off >>= 1) {
    l0 += __shfl_xor(l0, off, 64);
    l1 += __shfl_xor(l1, off, 64);
  }
  if (l == 0) {
    float z0 = l0 + b2[0], z1 = l1 + b2[1];
    float mx = fmaxf(z0, z1);
    float e0 = expf(z0 - mx), e1 = expf(z1 - mx);
    float s = 1.f / (e0 + e1);
    out[2 * m]     = e0 * s;
    out[2 * m + 1] = e1 * s;
  }
}

extern "C" void kernel_launch(void* const* d_in, const int* in_sizes, int n_in,
                              void* d_out, int out_size, void* d_ws, size_t ws_size,
                              hipStream_t stream) {
  (void)in_sizes; (void)n_in; (void)out_size; (void)ws_size;
  const int*   x   = (const int*)d_in[0];
  const float* emb = (const float*)d_in[1];
  const float* w1  = (const float*)d_in[2];
  const float* b1  = (const float*)d_in[3];
  const float* w2  = (const float*)d_in[4];
  const float* b2  = (const float*)d_in[5];
  float* out = (float*)d_out;
  char* ws = (char*)d_ws;
  bf16_t* embT = (bf16_t*)(ws + WS_EMBT);
  bf16_t* Wbf  = (bf16_t*)(ws + WS_W1);
  float*  hp   = (float*)(ws + WS_HP);

  hipLaunchKernelGGL(k_prep,  dim3(2368), dim3(256), 0, stream, emb, w1, embT, Wbf);
  hipLaunchKernelGGL(k_gemm,  dim3(BATCH/128, HIDDEN/128, SPLITK), dim3(256), 0, stream,
                     x, embT, Wbf, hp);
  hipLaunchKernelGGL(k_final, dim3(BATCH/4), dim3(256), 0, stream, hp, b1, w2, b2, out);
}

// Round 4
// 391.576 us; speedup vs baseline: 1.1110x; 1.1110x over previous
//
#include <hip/hip_runtime.h>
#include <hip/hip_bf16.h>
#include <stdint.h>

// Problem constants
#define BATCH   4096
#define CONTENT 200
#define EMBED   128
#define HIDDEN  1024
#define KDIM    (CONTENT*EMBED)   // 25600
#define SPLITK  4                 // 4 chunks x 100 K-tiles(64) = 50 tokens each

typedef __bf16 bf16_t;
typedef __bf16 bf16x8 __attribute__((ext_vector_type(8)));
typedef float  f32x4  __attribute__((ext_vector_type(4)));

// Workspace layout (bytes)
#define WS_EMBT  0ull                      // emb bf16 [50000][128] = 12,800,000 B
#define WS_W1    12800000ull               // w1 bf16 [1024][25600] = 52,428,800 B
#define WS_HP    65228800ull               // 4 x f32 [4096][1024]  = 67,108,864 B
#define HP_STRIDE 4194304ull               // floats per partial buffer

__device__ __forceinline__ void gload_lds16(const void* g, void* l) {
  __builtin_amdgcn_global_load_lds(
      (const __attribute__((address_space(1))) uint32_t*)g,
      (__attribute__((address_space(3))) uint32_t*)l, 16, 0, 0);
}

// ---------------- Kernel 1: fused prep — cast emb (zero row 0) + cast w1 ----------------
__global__ __launch_bounds__(256) void k_prep(const float* __restrict__ emb,
                                              const float* __restrict__ w1,
                                              bf16_t* __restrict__ embT,
                                              bf16_t* __restrict__ w1T) {
  if (blockIdx.x < 320) {
    const int NU = 800000;                 // 50000*128/8
    int stride = 320 * 256;
    for (int u = blockIdx.x * 256 + threadIdx.x; u < NU; u += stride) {
      const float4* s = (const float4*)(emb + (size_t)u * 8);
      float4 f0 = s[0], f1 = s[1];
      float sc = (u >> 4) == 0 ? 0.0f : 1.0f;   // padding_idx = 0
      bf16x8 r;
      r[0]=(bf16_t)(f0.x*sc); r[1]=(bf16_t)(f0.y*sc); r[2]=(bf16_t)(f0.z*sc); r[3]=(bf16_t)(f0.w*sc);
      r[4]=(bf16_t)(f1.x*sc); r[5]=(bf16_t)(f1.y*sc); r[6]=(bf16_t)(f1.z*sc); r[7]=(bf16_t)(f1.w*sc);
      *(bf16x8*)(embT + (size_t)u * 8) = r;
    }
  } else {
    const long long NU = 3276800;          // 1024*25600/8
    long long stride = 2048LL * 256;
    for (long long u = (long long)(blockIdx.x - 320) * 256 + threadIdx.x; u < NU; u += stride) {
      const float4* s = (const float4*)(w1 + u * 8);
      float4 f0 = s[0], f1 = s[1];
      bf16x8 r;
      r[0]=(bf16_t)f0.x; r[1]=(bf16_t)f0.y; r[2]=(bf16_t)f0.z; r[3]=(bf16_t)f0.w;
      r[4]=(bf16_t)f1.x; r[5]=(bf16_t)f1.y; r[6]=(bf16_t)f1.z; r[7]=(bf16_t)f1.w;
      *(bf16x8*)(w1T + u * 8) = r;
    }
  }
}

// ---------------- Kernel 2: fused gather-GEMM, 256x256 8-phase counted-vmcnt ----------------
// buf0 (bytes 0..65535) holds even K-tiles, buf1 (65536..) odd K-tiles.
// A-half h = rows {h*64..h*64+63, 128+h*64..191+h*64}; B-half h = rows with bit5==h.
// Iter j phases compute K-tile 2j (p0-p3, quads (0,0)(0,1)(1,0)(1,1)) and 2j+1 (p4-p7).
// Issue map: p0:A1(2j+1) p1:B1(2j+1) p2:A0(2j+2) p3:B0(2j+2)+vmcnt(4)
//            p4:A1(2j+2) p5:B1(2j+2) p6:A0(2j+3) p7:B0(2j+3)+vmcnt(4)
// Proof sketch: every region overwritten was fully read >=1 barrier earlier; every
// half read at phase p was drained by the vmcnt(4) (keeps only 2 newest halves)
// at the preceding p3/p7 boundary.  x-gather loads issue at iter start (older
// than the kept set -> counts unaffected).
__global__ __launch_bounds__(512, 2) void k_gemm(const int* __restrict__ x,
                                                 const bf16_t* __restrict__ embT,
                                                 const bf16_t* __restrict__ W,
                                                 float* __restrict__ hp) {
  __shared__ char smem[131072];
  const int tid = threadIdx.x;
  const int wid = tid >> 6, l = tid & 63;
  // bijective XCD swizzle: 256 blocks, 8 XCDs, 32 consecutive origs per XCD
  const int orig = (blockIdx.x & 7) * 32 + (blockIdx.x >> 3);
  const int m0 = (orig & 15) * 256;
  const int n0 = ((orig >> 4) & 3) * 256;
  const int chunk = orig >> 6;
  const int cb100 = chunk * 100;          // chunk K-tile base (global K-tile idx)
  const int T0 = chunk * 50;              // chunk token base

  // ---- staging constants
  const int sg16 = ((l & 7) ^ (l >> 3)) * 16;   // pre-swizzled source k-slot byte
  const char* embB = (const char*)embT;
  const char* Wb = (const char*)W;
  const int wq = wid >> 2, wm = wid & 3;
  size_t brow[2];
  #pragma unroll
  for (int rd = 0; rd < 2; ++rd)
    brow[rd] = (size_t)(n0 + rd*128 + wq*64 + wm*8 + (l>>3)) * (size_t)(KDIM*2) + sg16;
  int xrow[4];                                   // f = rd*2 + h
  #pragma unroll
  for (int f = 0; f < 4; ++f)
    xrow[f] = (m0 + (f>>1)*128 + (f&1)*64 + (tid>>3)) * CONTENT;

  // ---- fragment constants
  const int wr = wq, wc = wm;             // 2 M-waves x 4 N-waves
  const int lane_r = l & 15, g = l >> 4;
  const int aoff = wr*16384 + lane_r*128;
  const int boff = 32768 + wc*8192 + lane_r*128;
  const int s0 = ((0*4 + g) ^ (lane_r & 7)) * 16;
  const int s1 = ((1*4 + g) ^ (lane_r & 7)) * 16;

#define ISSUE_A(BUF, H, XA, KOFF)                                             \
  { gload_lds16(embB + (size_t)XA[0*2+(H)]*256 + (KOFF) + sg16,               \
                smem + (BUF) + 0*16384 + (H)*8192 + wid*1024);                \
    gload_lds16(embB + (size_t)XA[1*2+(H)]*256 + (KOFF) + sg16,               \
                smem + (BUF) + 1*16384 + (H)*8192 + wid*1024); }
#define ISSUE_B(BUF, H, LT)                                                   \
  { const int lt_ = (LT) > 99 ? 99 : (LT);                                    \
    const size_t ko_ = (size_t)(cb100 + lt_) * 128 + (H)*1638400u;            \
    gload_lds16(Wb + brow[0] + ko_,                                           \
                smem + (BUF) + 32768 + 0*16384 + wq*8192 + (H)*4096 + wm*1024); \
    gload_lds16(Wb + brow[1] + ko_,                                           \
                smem + (BUF) + 32768 + 1*16384 + wq*8192 + (H)*4096 + wm*1024); }

#define PHASE(IH, JH, CB, ISSUE_STMT, TAIL)                                   \
  { bf16x8 af[4][2], bfr[2][2];                                               \
    _Pragma("unroll")                                                         \
    for (int ii = 0; ii < 4; ++ii) {                                          \
      af[ii][0] = *(const bf16x8*)(smem + (CB) + aoff + (IH)*8192 + ii*2048 + s0); \
      af[ii][1] = *(const bf16x8*)(smem + (CB) + aoff + (IH)*8192 + ii*2048 + s1); \
    }                                                                         \
    _Pragma("unroll")                                                         \
    for (int jj = 0; jj < 2; ++jj) {                                          \
      bfr[jj][0] = *(const bf16x8*)(smem + (CB) + boff + (JH)*4096 + jj*2048 + s0); \
      bfr[jj][1] = *(const bf16x8*)(smem + (CB) + boff + (JH)*4096 + jj*2048 + s1); \
    }                                                                         \
    ISSUE_STMT                                                                \
    __builtin_amdgcn_s_barrier();                                             \
    asm volatile("s_waitcnt lgkmcnt(0)" ::: "memory");                        \
    __builtin_amdgcn_s_setprio(1);                                            \
    _Pragma("unroll")                                                         \
    for (int ii = 0; ii < 4; ++ii)                                            \
      _Pragma("unroll")                                                       \
      for (int jj = 0; jj < 2; ++jj) {                                        \
        acc[(IH)*4+ii][(JH)*2+jj] = __builtin_amdgcn_mfma_f32_16x16x32_bf16(  \
            af[ii][0], bfr[jj][0], acc[(IH)*4+ii][(JH)*2+jj], 0, 0, 0);       \
        acc[(IH)*4+ii][(JH)*2+jj] = __builtin_amdgcn_mfma_f32_16x16x32_bf16(  \
            af[ii][1], bfr[jj][1], acc[(IH)*4+ii][(JH)*2+jj], 0, 0, 0);       \
      }                                                                       \
    __builtin_amdgcn_s_setprio(0);                                            \
    TAIL                                                                      \
    __builtin_amdgcn_s_barrier(); }

  f32x4 acc[8][4];
  #pragma unroll
  for (int i = 0; i < 8; ++i)
    #pragma unroll
    for (int j = 0; j < 4; ++j)
      acc[i][j] = (f32x4){0.f, 0.f, 0.f, 0.f};

  // ---- prologue: tile0 (A0,A1,B0,B1) + tile1 (A0,B0); leave tile1 halves in flight
  int xcur[4], xnxt[4];
  #pragma unroll
  for (int f = 0; f < 4; ++f) xcur[f] = x[xrow[f] + T0];
  #pragma unroll
  for (int f = 0; f < 4; ++f) xnxt[f] = x[xrow[f] + T0 + 1];
  ISSUE_A(0, 0, xcur, 0)
  ISSUE_A(0, 1, xcur, 0)
  ISSUE_B(0, 0, 0)
  ISSUE_B(0, 1, 0)
  ISSUE_A(65536, 0, xcur, 128)
  ISSUE_B(65536, 0, 1)
  asm volatile("s_waitcnt vmcnt(4)" ::: "memory");   // tile0 drained; tile1 A0/B0 in flight
  __builtin_amdgcn_s_barrier();

  for (int j = 0; j < 50; ++j) {
    int tnew = T0 + j + 2; if (tnew > CONTENT - 1) tnew = CONTENT - 1;
    int xnew[4];
    #pragma unroll
    for (int f = 0; f < 4; ++f) xnew[f] = x[xrow[f] + tnew];

    PHASE(0,0, 0,     { ISSUE_A(65536, 1, xcur, 128); }, {})
    PHASE(0,1, 0,     { ISSUE_B(65536, 1, 2*j+1); }, {})
    PHASE(1,0, 0,     { ISSUE_A(0, 0, xnxt, 0); }, {})
    PHASE(1,1, 0,     { ISSUE_B(0, 0, 2*j+2); },
                      { asm volatile("s_waitcnt vmcnt(4)" ::: "memory"); })
    PHASE(0,0, 65536, { ISSUE_A(0, 1, xnxt, 0); }, {})
    PHASE(0,1, 65536, { ISSUE_B(0, 1, 2*j+2); }, {})
    PHASE(1,0, 65536, { ISSUE_A(65536, 0, xnxt, 128); }, {})
    PHASE(1,1, 65536, { ISSUE_B(65536, 0, 2*j+3); },
                      { asm volatile("s_waitcnt vmcnt(4)" ::: "memory"); })

    #pragma unroll
    for (int f = 0; f < 4; ++f) { xcur[f] = xnxt[f]; xnxt[f] = xnew[f]; }
  }
#undef PHASE
#undef ISSUE_A
#undef ISSUE_B

  asm volatile("s_waitcnt vmcnt(0)" ::: "memory");

  // Epilogue: C/D layout col = lane&15, row = (lane>>4)*4 + reg  [HW-verified]
  float* hout = hp + (size_t)chunk * HP_STRIDE;
  const int colBase = n0 + wc * 64 + lane_r;
  const int rowBase = m0 + wr * 128 + (l >> 4) * 4;
  #pragma unroll
  for (int i = 0; i < 8; ++i)
    #pragma unroll
    for (int jj = 0; jj < 4; ++jj)
      #pragma unroll
      for (int r = 0; r < 4; ++r)
        hout[(size_t)(rowBase + i * 16 + r) * HIDDEN + colBase + jj * 16] = acc[i][jj][r];
}

// ---------------- Kernel 3: sum partials + bias + relu + layer2 + softmax ----------------
__global__ __launch_bounds__(256) void k_final(const float* __restrict__ hp,
                                               const float* __restrict__ b1,
                                               const float* __restrict__ w2,
                                               const float* __restrict__ b2,
                                               float* __restrict__ out) {
  const int tid = threadIdx.x;
  const int w = tid >> 6, l = tid & 63;
  const int m = blockIdx.x * 4 + w;     // one wave per batch row
  const float* r0 = hp + (size_t)m * HIDDEN;
  const float* r1 = r0 + HP_STRIDE;
  const float* r2 = r1 + HP_STRIDE;
  const float* r3 = r2 + HP_STRIDE;
  float l0 = 0.f, l1 = 0.f;
  #pragma unroll
  for (int t = 0; t < 4; ++t) {
    int j = t * 256 + l * 4;
    float4 p0 = *(const float4*)(r0 + j);
    float4 p1 = *(const float4*)(r1 + j);
    float4 p2 = *(const float4*)(r2 + j);
    float4 p3 = *(const float4*)(r3 + j);
    float4 bb = *(const float4*)(b1 + j);
    float4 wa = *(const float4*)(w2 + j);
    float4 wb = *(const float4*)(w2 + HIDDEN + j);
    float h;
    h = p0.x + p1.x + p2.x + p3.x + bb.x; h = fmaxf(h, 0.f); l0 += h * wa.x; l1 += h * wb.x;
    h = p0.y + p1.y + p2.y + p3.y + bb.y; h = fmaxf(h, 0.f); l0 += h * wa.y; l1 += h * wb.y;
    h = p0.z + p1.z + p2.z + p3.z + bb.z; h = fmaxf(h, 0.f); l0 += h * wa.z; l1 += h * wb.z;
    h = p0.w + p1.w + p2.w + p3.w + bb.w; h = fmaxf(h, 0.f); l0 += h * wa.w; l1 += h * wb.w;
  }
  #pragma unroll
  for (int off = 32; off > 0; off >>= 1) {
    l0 += __shfl_xor(l0, off, 64);
    l1 += __shfl_xor(l1, off, 64);
  }
  if (l == 0) {
    float z0 = l0 + b2[0], z1 = l1 + b2[1];
    float mx = fmaxf(z0, z1);
    float e0 = expf(z0 - mx), e1 = expf(z1 - mx);
    float s = 1.f / (e0 + e1);
    out[2 * m]     = e0 * s;
    out[2 * m + 1] = e1 * s;
  }
}

extern "C" void kernel_launch(void* const* d_in, const int* in_sizes, int n_in,
                              void* d_out, int out_size, void* d_ws, size_t ws_size,
                              hipStream_t stream) {
  (void)in_sizes; (void)n_in; (void)out_size; (void)ws_size;
  const int*   x   = (const int*)d_in[0];
  const float* emb = (const float*)d_in[1];
  const float* w1  = (const float*)d_in[2];
  const float* b1  = (const float*)d_in[3];
  const float* w2  = (const float*)d_in[4];
  const float* b2  = (const float*)d_in[5];
  float* out = (float*)d_out;
  char* ws = (char*)d_ws;
  bf16_t* embT = (bf16_t*)(ws + WS_EMBT);
  bf16_t* Wbf  = (bf16_t*)(ws + WS_W1);
  float*  hp   = (float*)(ws + WS_HP);

  hipLaunchKernelGGL(k_prep,  dim3(2368), dim3(256), 0, stream, emb, w1, embT, Wbf);
  hipLaunchKernelGGL(k_gemm,  dim3(256), dim3(512), 0, stream, x, embT, Wbf, hp);
  hipLaunchKernelGGL(k_final, dim3(BATCH/4), dim3(256), 0, stream, hp, b1, w2, b2, out);
}